// Round 1
// baseline (256.969 us; speedup 1.0000x reference)
//
#include <hip/hip_runtime.h>

#define D_K 576
#define NSLAB 18         // 576 / 32
#define LBDA_INV 2.0f    // 1/lbda, lbda=0.5
#define HALF_LBDA 0.5f
#define EPS 0.01f
#define DSTRIDE 136      // 128 + 8 bf16 pad (DP scratch)
#define SLAB_USHORTS 4096  // 128 rows x 32 cols bf16 per slab buffer

typedef __attribute__((ext_vector_type(8))) short short8;
typedef __attribute__((ext_vector_type(4))) short short4v;
typedef __attribute__((ext_vector_type(4))) float f32x4;

__device__ inline short f2bf(float f) {
    unsigned u = __float_as_uint(f);
    u += 0x7FFF + ((u >> 16) & 1);   // round-to-nearest-even
    return (short)(u >> 16);
}
__device__ inline float bf2f(unsigned short s) {
    return __uint_as_float(((unsigned)s) << 16);
}

// ---------------- soft-min helpers (lbda = 0.5) ----------------
__device__ inline float softmin3(float a, float b, float c) {
    float mn = fminf(a, fminf(b, c));
    float s = __expf(-LBDA_INV * (a - mn)) + __expf(-LBDA_INV * (b - mn)) +
              __expf(-LBDA_INV * (c - mn));
    return mn - HALF_LBDA * __logf(s);
}
__device__ inline float softmin2(float a, float b) {
    float mn = fminf(a, b);
    float s = __expf(-LBDA_INV * (a - mn)) + __expf(-LBDA_INV * (b - mn));
    return mn - HALF_LBDA * __logf(s);
}

// OTAM DP over an 8x8 dist tile; element (l,s) at d[l*RS + s*CS].
template <int RS, int CS>
__device__ float otam_dp(const float* d) {
    float prev[10], cur[10];
    prev[0] = 0.f;
#pragma unroll
    for (int m = 1; m <= 8; ++m) prev[m] = prev[m - 1] + d[0 * RS + (m - 1) * CS];
    prev[9] = prev[8];  // pad col, d=0
#pragma unroll
    for (int l = 1; l < 8; ++l) {
        cur[0] = 0.f;
        cur[1] = d[l * RS + 0 * CS] + softmin3(prev[0], 0.f, prev[1]);
#pragma unroll
        for (int m = 2; m <= 8; ++m)
            cur[m] = d[l * RS + (m - 1) * CS] + softmin2(prev[m - 1], cur[m - 1]);
        cur[9] = softmin3(prev[8], cur[8], prev[9]);
#pragma unroll
        for (int m = 0; m < 10; ++m) prev[m] = cur[m];
    }
    return prev[9];
}

// ---------------- single fused kernel ----------------
// Per block: 128 q-rows x 128 s-rows. K-loop stages f32 -> bf16 slabs (128x32)
// into double-buffered LDS (conversion on the fly, norms accumulated inline),
// MFMA 16x16x32 bf16 accumulates the 128x128 GEMM tile, then epilogue + OTAM DP.
// LDS chunk layout per slab: chunk p = c_in*128 + (r ^ (c_in<<1)) holds
// X[r][slab*32 + c_in*8 .. +7] (XOR swizzle kills the 4-way ds_write conflict;
// fragment ds_read_b128 stays 16-lane-contiguous = conflict-free).
__global__ __launch_bounds__(256, 2) void fused_kernel(
        const float* __restrict__ sup, const float* __restrict__ qry,
        float* __restrict__ out) {
    __shared__ unsigned short As[2][SLAB_USHORTS];   // 16 KB
    __shared__ unsigned short Bs[2][SLAB_USHORTS];   // 16 KB
    __shared__ unsigned short Ds[128 * DSTRIDE];     // 34 KB
    __shared__ float qn_l[128], sn_l[128];

    const int t = threadIdx.x;
    // XCD swizzle: 4 blocks sharing a qblk land on the same XCD -> A reuse in L2
    const int b = blockIdx.x;
    const int xcd = b & 7, s2 = b >> 3;
    const int sblk = s2 >> 4;                 // 0..3
    const int qblk = xcd * 16 + (s2 & 15);    // 0..127

    const float* qsrc = qry + (size_t)qblk * 128 * D_K;
    const float* ssrc = sup + (size_t)sblk * 128 * D_K;

    // staging decomposition: thread t handles rows {i*32 + rr}, float4-col cc
    const int rr = t >> 3;        // 0..31
    const int cc = t & 7;         // 0..7 (8 float4 per 32-col slab row)
    const int c_in = cc >> 1, half = cc & 1;

    const int lane = t & 63;
    const int wave = t >> 6;
    const int wm = wave >> 1, wn = wave & 1;
    const int col16 = lane & 15, quad = lane >> 4;

    f32x4 acc[4][4];
#pragma unroll
    for (int i = 0; i < 4; ++i)
#pragma unroll
        for (int j = 0; j < 4; ++j) acc[i][j] = (f32x4){0.f, 0.f, 0.f, 0.f};

    // fragment read offsets (ushorts) and staging write offsets, XOR-swizzled
    int aoff[4], boff[4], woff[4];
#pragma unroll
    for (int mt = 0; mt < 4; ++mt)
        aoff[mt] = (quad * 128 + ((wm * 64 + mt * 16 + col16) ^ (quad << 1))) * 8;
#pragma unroll
    for (int nt = 0; nt < 4; ++nt)
        boff[nt] = (quad * 128 + ((wn * 64 + nt * 16 + col16) ^ (quad << 1))) * 8;
#pragma unroll
    for (int i = 0; i < 4; ++i)
        woff[i] = (c_in * 128 + ((i * 32 + rr) ^ (c_in << 1))) * 8 + half * 4;

    float ssA[4] = {0.f, 0.f, 0.f, 0.f}, ssB[4] = {0.f, 0.f, 0.f, 0.f};
    float4 va[4], vb[4];

    // ---- prologue: stage slab 0 into buffer 0 ----
#pragma unroll
    for (int i = 0; i < 4; ++i) {
        va[i] = *(const float4*)(qsrc + (size_t)(i * 32 + rr) * D_K + cc * 4);
        vb[i] = *(const float4*)(ssrc + (size_t)(i * 32 + rr) * D_K + cc * 4);
    }
#pragma unroll
    for (int i = 0; i < 4; ++i) {
        ssA[i] += va[i].x * va[i].x + va[i].y * va[i].y + va[i].z * va[i].z + va[i].w * va[i].w;
        ssB[i] += vb[i].x * vb[i].x + vb[i].y * vb[i].y + vb[i].z * vb[i].z + vb[i].w * vb[i].w;
        short4v oa = {f2bf(va[i].x), f2bf(va[i].y), f2bf(va[i].z), f2bf(va[i].w)};
        short4v ob = {f2bf(vb[i].x), f2bf(vb[i].y), f2bf(vb[i].z), f2bf(vb[i].w)};
        *(short4v*)(&As[0][woff[i]]) = oa;
        *(short4v*)(&Bs[0][woff[i]]) = ob;
    }
    __syncthreads();

    // ---- K loop: issue next-slab global loads EARLY, frag-read + MFMA current,
    //      convert + ds_write next slab LATE (T14 split), one barrier per slab ----
#pragma unroll
    for (int sl = 0; sl < NSLAB; ++sl) {
        const int cur = sl & 1;
        const bool more = (sl + 1) < NSLAB;
        if (more) {
            const int off = (sl + 1) * 32 + cc * 4;
#pragma unroll
            for (int i = 0; i < 4; ++i) {
                va[i] = *(const float4*)(qsrc + (size_t)(i * 32 + rr) * D_K + off);
                vb[i] = *(const float4*)(ssrc + (size_t)(i * 32 + rr) * D_K + off);
            }
        }
        short8 af[4], bq[4];
#pragma unroll
        for (int mt = 0; mt < 4; ++mt) af[mt] = *(const short8*)(&As[cur][aoff[mt]]);
#pragma unroll
        for (int nt = 0; nt < 4; ++nt) bq[nt] = *(const short8*)(&Bs[cur][boff[nt]]);
#pragma unroll
        for (int mt = 0; mt < 4; ++mt)
#pragma unroll
            for (int nt = 0; nt < 4; ++nt)
                acc[mt][nt] = __builtin_amdgcn_mfma_f32_16x16x32_bf16(
                    af[mt], bq[nt], acc[mt][nt], 0, 0, 0);
        if (more) {
            const int nb = cur ^ 1;
#pragma unroll
            for (int i = 0; i < 4; ++i) {
                ssA[i] += va[i].x * va[i].x + va[i].y * va[i].y + va[i].z * va[i].z + va[i].w * va[i].w;
                ssB[i] += vb[i].x * vb[i].x + vb[i].y * vb[i].y + vb[i].z * vb[i].z + vb[i].w * vb[i].w;
                short4v oa = {f2bf(va[i].x), f2bf(va[i].y), f2bf(va[i].z), f2bf(va[i].w)};
                short4v ob = {f2bf(vb[i].x), f2bf(vb[i].y), f2bf(vb[i].z), f2bf(vb[i].w)};
                *(short4v*)(&As[nb][woff[i]]) = oa;
                *(short4v*)(&Bs[nb][woff[i]]) = ob;
            }
        }
        __syncthreads();
    }

    // ---- norms: octet shfl-reduce the per-thread partials (rows i*32+rr) ----
#pragma unroll
    for (int i = 0; i < 4; ++i) {
        float a = ssA[i], s = ssB[i];
        a += __shfl_down(a, 4); a += __shfl_down(a, 2); a += __shfl_down(a, 1);
        s += __shfl_down(s, 4); s += __shfl_down(s, 2); s += __shfl_down(s, 1);
        if ((t & 7) == 0) {   // 32 lanes, rr = 0..31: rows i*32..i*32+31, unique
            qn_l[i * 32 + rr] = sqrtf(a);
            sn_l[i * 32 + rr] = sqrtf(s);
        }
    }
    __syncthreads();

    // ---- epilogue: dist = 1 - num * rcp(|q||s| + eps) -> Ds (bf16) ----
    // C/D layout: col = lane&15, row = quad*4 + reg
#pragma unroll
    for (int mt = 0; mt < 4; ++mt) {
#pragma unroll
        for (int reg = 0; reg < 4; ++reg) {
            int m = wm * 64 + mt * 16 + quad * 4 + reg;
            float qv = qn_l[m];
#pragma unroll
            for (int nt = 0; nt < 4; ++nt) {
                int n = wn * 64 + nt * 16 + col16;
                float sv = sn_l[n];
                float dist = 1.f - acc[mt][nt][reg] * __builtin_amdgcn_rcpf(qv * sv + EPS);
                Ds[m * DSTRIDE + n] = (unsigned short)f2bf(dist);
            }
        }
    }
    __syncthreads();

    // ---- DP phase: thread t owns pair (ql, sj) ----
    const int ql = t >> 4, sj = t & 15;
    float d[64];
#pragma unroll
    for (int l = 0; l < 8; ++l) {
        short8 rowv = *(const short8*)(&Ds[(ql * 8 + l) * DSTRIDE + sj * 8]);
#pragma unroll
        for (int j = 0; j < 8; ++j) d[l * 8 + j] = bf2f((unsigned short)rowv[j]);
    }
    float r1 = otam_dp<8, 1>(d);   // dists
    float r2 = otam_dp<1, 8>(d);   // dists^T
    int qg = qblk * 16 + ql, sg = sblk * 16 + sj;
    out[qg * 64 + sg] = -(r1 + r2);
}

extern "C" void kernel_launch(void* const* d_in, const int* in_sizes, int n_in,
                              void* d_out, int out_size, void* d_ws, size_t ws_size,
                              hipStream_t stream) {
    const float* sup = (const float*)d_in[0];   // [64, 8, 576]
    const float* qry = (const float*)d_in[1];   // [2048, 8, 576]
    float* out = (float*)d_out;                 // [2048, 64]
    (void)d_ws; (void)ws_size;                  // workspace no longer used
    fused_kernel<<<dim3(512), dim3(256), 0, stream>>>(sup, qry, out);
}

// Round 3
// 105.352 us; speedup vs baseline: 2.4391x; 2.4391x over previous
//
#include <hip/hip_runtime.h>

#define D_K 576
#define NSLAB 18         // 576 / 32
#define LBDA_INV 2.0f    // 1/lbda, lbda=0.5
#define HALF_LBDA 0.5f
#define EPS 0.01f
#define DSTRIDE 136      // 128 + 8 bf16 pad (DP scratch)
#define SLAB_USHORTS 4096  // 128 rows x 32 cols bf16 per slab buffer

typedef __attribute__((ext_vector_type(8))) short short8;
typedef __attribute__((ext_vector_type(4))) short short4v;
typedef __attribute__((ext_vector_type(4))) float f32x4;

__device__ inline short f2bf(float f) {
    unsigned u = __float_as_uint(f);
    u += 0x7FFF + ((u >> 16) & 1);   // round-to-nearest-even
    return (short)(u >> 16);
}
__device__ inline float bf2f(unsigned short s) {
    return __uint_as_float(((unsigned)s) << 16);
}

// ---------------- soft-min helpers (lbda = 0.5) ----------------
__device__ inline float softmin3(float a, float b, float c) {
    float mn = fminf(a, fminf(b, c));
    float s = __expf(-LBDA_INV * (a - mn)) + __expf(-LBDA_INV * (b - mn)) +
              __expf(-LBDA_INV * (c - mn));
    return mn - HALF_LBDA * __logf(s);
}
__device__ inline float softmin2(float a, float b) {
    float mn = fminf(a, b);
    float s = __expf(-LBDA_INV * (a - mn)) + __expf(-LBDA_INV * (b - mn));
    return mn - HALF_LBDA * __logf(s);
}

// OTAM DP over an 8x8 dist tile; element (l,s) at d[l*RS + s*CS].
template <int RS, int CS>
__device__ float otam_dp(const float* d) {
    float prev[10], cur[10];
    prev[0] = 0.f;
#pragma unroll
    for (int m = 1; m <= 8; ++m) prev[m] = prev[m - 1] + d[0 * RS + (m - 1) * CS];
    prev[9] = prev[8];  // pad col, d=0
#pragma unroll
    for (int l = 1; l < 8; ++l) {
        cur[0] = 0.f;
        cur[1] = d[l * RS + 0 * CS] + softmin3(prev[0], 0.f, prev[1]);
#pragma unroll
        for (int m = 2; m <= 8; ++m)
            cur[m] = d[l * RS + (m - 1) * CS] + softmin2(prev[m - 1], cur[m - 1]);
        cur[9] = softmin3(prev[8], cur[8], prev[9]);
#pragma unroll
        for (int m = 0; m < 10; ++m) prev[m] = cur[m];
    }
    return prev[9];
}

// ---------------- single fused kernel (spill-safe restructure) ----------------
// Per block: 128 q-rows x 128 s-rows. Rolled K-loop (9 iters x 2 slabs), statically
// named double buffers, ONE staging register set (va/vb) in flight. Per slab:
// issue next-slab f32 loads -> ds_read frags + 16 MFMA -> convert+ds_write next
// -> barrier. Norms accumulated inline; then epilogue + OTAM DP.
// LDS chunk layout per slab: chunk p = c_in*128 + (r ^ (c_in<<1)) holds
// X[r][slab*32 + c_in*8 .. +7] (XOR swizzle on BOTH write and read side).
__global__ __launch_bounds__(256, 2) void fused_kernel(
        const float* __restrict__ sup, const float* __restrict__ qry,
        float* __restrict__ out) {
    __shared__ unsigned short As0[SLAB_USHORTS], Bs0[SLAB_USHORTS];  // 16 KB
    __shared__ unsigned short As1[SLAB_USHORTS], Bs1[SLAB_USHORTS];  // 16 KB
    __shared__ unsigned short Ds[128 * DSTRIDE];                     // 34 KB
    __shared__ float qn_l[128], sn_l[128];

    const int t = threadIdx.x;
    // XCD swizzle: 4 blocks sharing a qblk land on the same XCD -> A reuse in L2
    const int b = blockIdx.x;
    const int xcd = b & 7, s2 = b >> 3;
    const int sblk = s2 >> 4;                 // 0..3
    const int qblk = xcd * 16 + (s2 & 15);    // 0..127

    const float* qsrc = qry + (size_t)qblk * 128 * D_K;
    const float* ssrc = sup + (size_t)sblk * 128 * D_K;

    // staging decomposition: thread t handles rows {i*32 + rr}, float4-col cc
    const int rr = t >> 3;        // 0..31
    const int cc = t & 7;         // 0..7 (8 float4 per 32-col slab row)
    const int c_in = cc >> 1, half = cc & 1;

    const int lane = t & 63;
    const int wave = t >> 6;
    const int wm = wave >> 1, wn = wave & 1;
    const int col16 = lane & 15, quad = lane >> 4;

    f32x4 acc[4][4];
#pragma unroll
    for (int i = 0; i < 4; ++i)
#pragma unroll
        for (int j = 0; j < 4; ++j) acc[i][j] = (f32x4){0.f, 0.f, 0.f, 0.f};

    // fragment read offsets (ushorts) and staging write offsets, XOR-swizzled
    int aoff[4], boff[4], woff[4];
#pragma unroll
    for (int mt = 0; mt < 4; ++mt)
        aoff[mt] = (quad * 128 + ((wm * 64 + mt * 16 + col16) ^ (quad << 1))) * 8;
#pragma unroll
    for (int nt = 0; nt < 4; ++nt)
        boff[nt] = (quad * 128 + ((wn * 64 + nt * 16 + col16) ^ (quad << 1))) * 8;
#pragma unroll
    for (int i = 0; i < 4; ++i)
        woff[i] = (c_in * 128 + ((i * 32 + rr) ^ (c_in << 1))) * 8 + half * 4;

    float ssA[4] = {0.f, 0.f, 0.f, 0.f}, ssB[4] = {0.f, 0.f, 0.f, 0.f};
    float4 va[4], vb[4];

    auto stage_load = [&](int sl) {
        const int off = sl * 32 + cc * 4;
#pragma unroll
        for (int i = 0; i < 4; ++i) {
            va[i] = *(const float4*)(qsrc + (size_t)(i * 32 + rr) * D_K + off);
            vb[i] = *(const float4*)(ssrc + (size_t)(i * 32 + rr) * D_K + off);
        }
    };
    auto stage_write = [&](unsigned short* __restrict__ A,
                           unsigned short* __restrict__ B) {
#pragma unroll
        for (int i = 0; i < 4; ++i) {
            ssA[i] += va[i].x * va[i].x + va[i].y * va[i].y +
                      va[i].z * va[i].z + va[i].w * va[i].w;
            ssB[i] += vb[i].x * vb[i].x + vb[i].y * vb[i].y +
                      vb[i].z * vb[i].z + vb[i].w * vb[i].w;
            short4v oa = {f2bf(va[i].x), f2bf(va[i].y), f2bf(va[i].z), f2bf(va[i].w)};
            short4v ob = {f2bf(vb[i].x), f2bf(vb[i].y), f2bf(vb[i].z), f2bf(vb[i].w)};
            *(short4v*)(&A[woff[i]]) = oa;
            *(short4v*)(&B[woff[i]]) = ob;
        }
    };
    auto compute = [&](const unsigned short* __restrict__ A,
                       const unsigned short* __restrict__ B) {
        short8 af[4], bq[4];
#pragma unroll
        for (int mt = 0; mt < 4; ++mt) af[mt] = *(const short8*)(&A[aoff[mt]]);
#pragma unroll
        for (int nt = 0; nt < 4; ++nt) bq[nt] = *(const short8*)(&B[boff[nt]]);
#pragma unroll
        for (int mt = 0; mt < 4; ++mt)
#pragma unroll
            for (int nt = 0; nt < 4; ++nt)
                acc[mt][nt] = __builtin_amdgcn_mfma_f32_16x16x32_bf16(
                    af[mt], bq[nt], acc[mt][nt], 0, 0, 0);
    };

    // ---- prologue: stage slab 0 into buffer 0 ----
    stage_load(0);
    stage_write(As0, Bs0);
    __syncthreads();

    // ---- K loop: 9 iterations x 2 slabs, one barrier per slab ----
#pragma unroll 1
    for (int sp = 0; sp < 9; ++sp) {
        stage_load(2 * sp + 1);          // issue early (T14)
        compute(As0, Bs0);               // slab 2sp
        stage_write(As1, Bs1);           // convert + ds_write late
        __syncthreads();
        if (sp < 8) stage_load(2 * sp + 2);
        compute(As1, Bs1);               // slab 2sp+1
        if (sp < 8) stage_write(As0, Bs0);
        __syncthreads();
    }

    // ---- norms: octet shfl-reduce the per-thread partials (rows i*32+rr) ----
#pragma unroll
    for (int i = 0; i < 4; ++i) {
        float a = ssA[i], s = ssB[i];
        a += __shfl_down(a, 4); a += __shfl_down(a, 2); a += __shfl_down(a, 1);
        s += __shfl_down(s, 4); s += __shfl_down(s, 2); s += __shfl_down(s, 1);
        if ((t & 7) == 0) {   // 32 lanes, rr = 0..31: rows i*32..i*32+31, unique
            qn_l[i * 32 + rr] = sqrtf(a);
            sn_l[i * 32 + rr] = sqrtf(s);
        }
    }
    __syncthreads();

    // ---- epilogue: dist = 1 - num * rcp(|q||s| + eps) -> Ds (bf16) ----
    // C/D layout: col = lane&15, row = quad*4 + reg
#pragma unroll
    for (int mt = 0; mt < 4; ++mt) {
#pragma unroll
        for (int reg = 0; reg < 4; ++reg) {
            int m = wm * 64 + mt * 16 + quad * 4 + reg;
            float qv = qn_l[m];
#pragma unroll
            for (int nt = 0; nt < 4; ++nt) {
                int n = wn * 64 + nt * 16 + col16;
                float sv = sn_l[n];
                float dist = 1.f - acc[mt][nt][reg] * __builtin_amdgcn_rcpf(qv * sv + EPS);
                Ds[m * DSTRIDE + n] = (unsigned short)f2bf(dist);
            }
        }
    }
    __syncthreads();

    // ---- DP phase: thread t owns pair (ql, sj) ----
    const int ql = t >> 4, sj = t & 15;
    float d[64];
#pragma unroll
    for (int l = 0; l < 8; ++l) {
        short8 rowv = *(const short8*)(&Ds[(ql * 8 + l) * DSTRIDE + sj * 8]);
#pragma unroll
        for (int j = 0; j < 8; ++j) d[l * 8 + j] = bf2f((unsigned short)rowv[j]);
    }
    float r1 = otam_dp<8, 1>(d);   // dists
    float r2 = otam_dp<1, 8>(d);   // dists^T
    int qg = qblk * 16 + ql, sg = sblk * 16 + sj;
    out[qg * 64 + sg] = -(r1 + r2);
}

extern "C" void kernel_launch(void* const* d_in, const int* in_sizes, int n_in,
                              void* d_out, int out_size, void* d_ws, size_t ws_size,
                              hipStream_t stream) {
    const float* sup = (const float*)d_in[0];   // [64, 8, 576]
    const float* qry = (const float*)d_in[1];   // [2048, 8, 576]
    float* out = (float*)d_out;                 // [2048, 64]
    (void)d_ws; (void)ws_size;                  // workspace unused
    fused_kernel<<<dim3(512), dim3(256), 0, stream>>>(sup, qry, out);
}